// Round 4
// baseline (367.544 us; speedup 1.0000x reference)
//
#include <hip/hip_runtime.h>
#include <cstdint>
#include <cstddef>

// ---------------------------------------------------------------------------
// Problem constants (LEVEL=16, LENGTH=64, TOPK=2, SIZE=512, BATCH=32)
// Inputs f32, outputs f32. Uniform absmax threshold 2.06 across outputs =>
// precision only matters for ORDERING near-ties (topk_n_idx needs |dn|<=2).
// Cheap path: f16 MFMA scores, f16 error only on the T path (sigma ~0.011).
// Rows with cheap top-2/3 gaps < DELTA=0.25 get exact f32 refinement over the
// candidate set {z: cheap[z] >= cheap_top2 - DELTA}.
//
// r6: top-5 dispatch is the harness's 474MB ws-poison fill (untouchable).
// r7: fused f32->f16 convert into GEMM A-staging, full-width 64m x 512n tile.
// r8: fragment-order LDS staging -> SQ_LDS_BANK_CONFLICT 7.4M -> 0 (verified).
// r9: conflicts gone but 98->122us, all pipes <14% => latency-serialization
//     at the per-step barrier (compiler emits vmcnt(0) before s_barrier).
// r10: LDS double-buffer FAILED (122us unchanged): __syncthreads() drains
//     vmcnt to 0 every step, killing the prefetch. Structural wall.
// r11: drop LDS/barriers ENTIRELY. B (512KB) is L2-resident across all 904
//     blocks; A's per-step 8KB tile is L1-resident across the block's 4
//     waves. Each wave loads fragments direct (A: f32x4 pairs + cvt, B:
//     f16x8 at 16KB stride) -- same bytes, same lanes as the LDS path.
//     No sync at all; ILP (unroll 2) + TLP hide L1/L2 latency.
// ---------------------------------------------------------------------------
#define B_DIM   32
#define L_DIM   48
#define NCELLS  904
#define SZ      512
#define NEGF    (-1e8f)
#define DELTA   0.25f
#define MAXC    32          // max candidates per row kept (z-ascending)

// d_out layout (f32), outputs concatenated flat in return order
#define OFF_S   1572864
#define OFF_N   1575936
#define OFF_L   1579008
#define OFF_R   1582080

typedef _Float16  f16x8 __attribute__((ext_vector_type(8)));
typedef float     f32x4 __attribute__((ext_vector_type(4)));

static __device__ __forceinline__ uint16_t f2bf(float f) {
    uint32_t u = __builtin_bit_cast(uint32_t, f);
    u += 0x7fffu + ((u >> 16) & 1u);
    return (uint16_t)(u >> 16);
}

#define GLD16(gp, lp) __builtin_amdgcn_global_load_lds(                        \
        (__attribute__((address_space(1))) void*)(gp),                         \
        (__attribute__((address_space(3))) void*)(lp), 16, 0, 0)

static __device__ __forceinline__ int level_off(int n) {
    return n * 64 - (n * (n - 1)) / 2;
}

// ---------------------------------------------------------------------------
// P0: matf16 = f16(64*mat)  (tiny: 1MB read)
// ---------------------------------------------------------------------------
__global__ __launch_bounds__(256)
void prep_mat(const float* __restrict__ mat, _Float16* __restrict__ mat16)
{
    const size_t j = ((size_t)blockIdx.x * 256 + threadIdx.x) * 8;
    const float4 c = *(const float4*)(mat + j);
    const float4 d = *(const float4*)(mat + j + 4);
    f16x8 w;
    w[0]=(_Float16)(c.x*64.f); w[1]=(_Float16)(c.y*64.f);
    w[2]=(_Float16)(c.z*64.f); w[3]=(_Float16)(c.w*64.f);
    w[4]=(_Float16)(d.x*64.f); w[5]=(_Float16)(d.y*64.f);
    w[6]=(_Float16)(d.z*64.f); w[7]=(_Float16)(d.w*64.f);
    *(f16x8*)(mat16 + j) = w;
}

// ---------------------------------------------------------------------------
// K1: T'[m,e] = sum_d f16(16*A[m,d]) * B16[e,d]   (A f32 in HBM). Tile
// 64m x 512n (full N), grid 904 -> A fetched once from HBM. BK=32.
// 4 waves: wave w owns n-range [128w,128w+128). T' is 1024x true value.
//
// r11: NO LDS, NO BARRIERS. Fragment loads direct from global:
//   A-frag af[mi], lane l: rows m0+mi*16+(l&15), k = k0+(l>>4)*8..+8,
//     loaded as 2 x f32x4 (L1-hit after first wave touches the 8KB tile),
//     converted x16 -> f16 in regs.
//   B-frag bf[ni], lane l: row wave*128+ni*16+(l&15), k = k0+(l>>4)*8..+8,
//     one f16x8 load (16B) at 16KB row-block stride (L2-resident, 512KB).
// Waves free-run; compiler pipelines loads of step k+1 under step k's MFMAs
// (unroll 2), per-use vmcnt instead of drain-to-0.
// ---------------------------------------------------------------------------
__global__ __launch_bounds__(256, 2)
void gemm_fused(const float* __restrict__ A,        // chart_h f32 [57856][512]
                const _Float16* __restrict__ Bm,    // mat16 [512][512]
                _Float16* __restrict__ C)           // T16 [57856][512]
{
    const int t = threadIdx.x;
    const int wave = t >> 6, lane = t & 63;
    const int m0 = blockIdx.x * 64;
    const int col_l = lane & 15, quad = lane >> 4;

    f32x4 acc[4][8];
#pragma unroll
    for (int i = 0; i < 4; ++i)
#pragma unroll
        for (int j = 0; j < 8; ++j) acc[i][j] = (f32x4){0.f, 0.f, 0.f, 0.f};

    // per-lane fragment bases
    const float*    abase = A  + (size_t)(m0 + col_l) * 512 + quad * 8;
    const _Float16* bbase = Bm + (size_t)(wave * 128 + col_l) * 512 + quad * 8;

#pragma unroll 2
    for (int ks = 0; ks < 16; ++ks) {
        const int k0 = ks * 32;

        f16x8 af[4];
#pragma unroll
        for (int mi = 0; mi < 4; ++mi) {
            const float* ap = abase + (size_t)(mi * 16) * 512 + k0;
            const f32x4 p0 = *(const f32x4*)ap;
            const f32x4 p1 = *(const f32x4*)(ap + 4);
#pragma unroll
            for (int j = 0; j < 4; ++j) {
                af[mi][j]     = (_Float16)(p0[j] * 16.f);
                af[mi][j + 4] = (_Float16)(p1[j] * 16.f);
            }
        }
#pragma unroll
        for (int ni = 0; ni < 8; ++ni) {
            const f16x8 bf = *(const f16x8*)(bbase + (size_t)(ni * 16) * 512 + k0);
#pragma unroll
            for (int mi = 0; mi < 4; ++mi)
                acc[mi][ni] = __builtin_amdgcn_mfma_f32_16x16x32_f16(
                    af[mi], bf, acc[mi][ni], 0, 0, 0);
        }
    }

    // epilogue: C/D layout col=lane&15, row=quad*4+reg
#pragma unroll
    for (int ni = 0; ni < 8; ++ni) {
        const int ncol = wave * 128 + ni * 16 + col_l;
#pragma unroll
        for (int mi = 0; mi < 4; ++mi) {
            const int mrow = m0 + mi * 16 + quad * 4;
#pragma unroll
            for (int r = 0; r < 4; ++r)
                C[(size_t)(mrow + r) * 512 + ncol] = (_Float16)acc[mi][ni][r];
        }
    }
}

// ---------------------------------------------------------------------------
// shared epilogue helpers
// ---------------------------------------------------------------------------
static __device__ __forceinline__ void emit_outputs(
    int row, int i1, int i2, float v1, float v2, float* out)
{
    out[OFF_S + row * 2 + 0] = v1;
    out[OFF_S + row * 2 + 1] = v2;
    out[OFF_N + row * 2 + 0] = (float)(i1 >> 2);
    out[OFF_N + row * 2 + 1] = (float)(i2 >> 2);
    out[OFF_L + row * 2 + 0] = (float)((i1 >> 1) & 1);
    out[OFF_L + row * 2 + 1] = (float)((i2 >> 1) & 1);
    out[OFF_R + row * 2 + 0] = (float)(i1 & 1);
    out[OFF_R + row * 2 + 1] = (float)(i2 & 1);
}

static __device__ __forceinline__ void gather_x(
    int row, int pos, int b, const int* top_z,
    const float* __restrict__ chart_h, uint16_t* __restrict__ X, int tid)
{
#pragma unroll
    for (int kq = 0; kq < 2; ++kq) {
        const int z = top_z[kq];
        const int n = z >> 2, lk = (z >> 1) & 1, rk = z & 1;
        const int lcell = level_off(n) + pos;
        const int rcell = level_off(15 - n) + pos + n + 1;
        const float* srcl = chart_h + ((size_t)(lk * B_DIM + b) * NCELLS + lcell) * SZ;
        const float* srcr = chart_h + ((size_t)(rk * B_DIM + b) * NCELLS + rcell) * SZ;
        uint16_t* dst = X + ((size_t)row * 2 + kq) * 1024;
        const int e = tid * 2;
        const float2 a = *(const float2*)(srcl + e);
        const float2 c = *(const float2*)(srcr + e);
        *(uint32_t*)(dst + e)       = (uint32_t)f2bf(a.x) | ((uint32_t)f2bf(a.y) << 16);
        *(uint32_t*)(dst + 512 + e) = (uint32_t)f2bf(c.x) | ((uint32_t)f2bf(c.y) << 16);
    }
}

// ---------------------------------------------------------------------------
// K2: cheap scores (lh f32 x T16 f16), top-3, near-tie flagging + candidate
// queue (ballot compaction). Clean rows emit outputs + gather X here.
// ---------------------------------------------------------------------------
__global__ __launch_bounds__(256)
void score_topk(const float* __restrict__ chart_h,   // f32
                const _Float16* __restrict__ T16,    // x1024
                const float* __restrict__ chart_s,
                uint32_t* __restrict__ items,        // queue entries (row<<6|z)
                int* __restrict__ rowbase,           // [1536]
                int* __restrict__ counter,           // 1 int, pre-zeroed
                int* __restrict__ flags,             // [1536]: nc (0 = clean)
                uint16_t* __restrict__ X,
                float* __restrict__ out)
{
    const int b   = blockIdx.x / L_DIM;
    const int pos = blockIdx.x % L_DIM;
    const int row = blockIdx.x;
    const int wave = threadIdx.x >> 6, lane = threadIdx.x & 63;

    __shared__ float s_sh[64];
    __shared__ int top_z[2];
    __shared__ int flag_sh;

#pragma unroll
    for (int ni = 0; ni < 4; ++ni) {
        const int n = wave * 4 + ni;
        const int lcell = level_off(n) + pos;
        const int rcell = level_off(15 - n) + pos + n + 1;

        const float* lp0 = chart_h + ((size_t)(0 * B_DIM + b) * NCELLS + lcell) * SZ + lane * 8;
        const float* lp1 = chart_h + ((size_t)(1 * B_DIM + b) * NCELLS + lcell) * SZ + lane * 8;
        const float4 l0a = *(const float4*)lp0, l0b = *(const float4*)(lp0 + 4);
        const float4 l1a = *(const float4*)lp1, l1b = *(const float4*)(lp1 + 4);
        const f16x8 t0 = *(const f16x8*)(T16 + ((size_t)(0 * B_DIM + b) * NCELLS + rcell) * SZ + lane * 8);
        const f16x8 t1 = *(const f16x8*)(T16 + ((size_t)(1 * B_DIM + b) * NCELLS + rcell) * SZ + lane * 8);

        float l0[8] = {l0a.x, l0a.y, l0a.z, l0a.w, l0b.x, l0b.y, l0b.z, l0b.w};
        float l1[8] = {l1a.x, l1a.y, l1a.z, l1a.w, l1b.x, l1b.y, l1b.z, l1b.w};

        float d00 = 0.f, d01 = 0.f, d10 = 0.f, d11 = 0.f;
#pragma unroll
        for (int j = 0; j < 8; ++j) {
            const float c0 = (float)t0[j], c1 = (float)t1[j];
            d00 += l0[j] * c0; d01 += l0[j] * c1;
            d10 += l1[j] * c0; d11 += l1[j] * c1;
        }
#pragma unroll
        for (int o = 32; o > 0; o >>= 1) {
            d00 += __shfl_down(d00, o);
            d01 += __shfl_down(d01, o);
            d10 += __shfl_down(d10, o);
            d11 += __shfl_down(d11, o);
        }
        if (lane == 0) {
            const float ls0 = chart_s[(size_t)(0 * B_DIM + b) * NCELLS + lcell];
            const float ls1 = chart_s[(size_t)(1 * B_DIM + b) * NCELLS + lcell];
            const float rs0 = chart_s[(size_t)(0 * B_DIM + b) * NCELLS + rcell];
            const float rs1 = chart_s[(size_t)(1 * B_DIM + b) * NCELLS + rcell];
            const float inv = 1.0f / 1024.0f;        // undo x1024 on T'
            s_sh[n * 4 + 0] = d00 * inv + ls0 + rs0;
            s_sh[n * 4 + 1] = d01 * inv + ls0 + rs1;
            s_sh[n * 4 + 2] = d10 * inv + ls1 + rs0;
            s_sh[n * 4 + 3] = d11 * inv + ls1 + rs1;
        }
    }
    __syncthreads();

    if (threadIdx.x < 64) {
        float v = s_sh[lane];
        if (lane == 2 || lane == 3) v = NEGF;        // penalty mask
        float v1 = v; int i1 = lane;
#pragma unroll
        for (int o = 32; o > 0; o >>= 1) {
            float ov = __shfl_down(v1, o);
            int   oi = __shfl_down(i1, o);
            if (ov > v1 || (ov == v1 && oi < i1)) { v1 = ov; i1 = oi; }
        }
        v1 = __shfl(v1, 0); i1 = __shfl(i1, 0);
        float v2 = (lane == i1) ? -3.4e38f : v; int i2 = lane;
#pragma unroll
        for (int o = 32; o > 0; o >>= 1) {
            float ov = __shfl_down(v2, o);
            int   oi = __shfl_down(i2, o);
            if (ov > v2 || (ov == v2 && oi < i2)) { v2 = ov; i2 = oi; }
        }
        v2 = __shfl(v2, 0); i2 = __shfl(i2, 0);
        float v3 = (lane == i1 || lane == i2) ? -3.4e38f : v;
#pragma unroll
        for (int o = 32; o > 0; o >>= 1) {
            const float ov = __shfl_down(v3, o);
            if (ov > v3) v3 = ov;
        }
        v3 = __shfl(v3, 0);

        const int f = (v1 - v2 < DELTA) || (v2 - v3 < DELTA);
        const bool cand = (v >= v2 - DELTA);
        const unsigned long long mask = __ballot(cand);
        const int nc_full = __popcll(mask);
        const int nc = nc_full < MAXC ? nc_full : MAXC;
        int base = 0;
        if (lane == 0) {
            flags[row] = f ? nc : 0;
            flag_sh = f;
            if (f) base = atomicAdd(counter, nc);
            rowbase[row] = base;
            top_z[0] = i1; top_z[1] = i2;
            if (!f) emit_outputs(row, i1, i2, v1, v2, out);
        }
        base = __shfl(base, 0);
        if (f && cand) {
            const int rank = __popcll(mask & ((1ull << lane) - 1ull));
            if (rank < MAXC) items[base + rank] = ((uint32_t)row << 6) | (uint32_t)lane;
        }
    }
    __syncthreads();

    if (!flag_sh)
        gather_x(row, pos, b, top_z, chart_h, X, threadIdx.x);
}

// ---------------------------------------------------------------------------
// K3a: exact f32 eval, block per ITEM PAIR (both items share the 1MB mat
// sweep). Waves split the e-range; lane owns rh[8*lane..+8) in regs.
// ---------------------------------------------------------------------------
__global__ __launch_bounds__(256)
void refine_eval(const float* __restrict__ chart_h,
                 const float* __restrict__ chart_s,
                 const float* __restrict__ mat,
                 const uint32_t* __restrict__ items,
                 const int* __restrict__ counter,
                 float* __restrict__ exval)
{
    const int total = *counter;
    const int t = threadIdx.x;
    const int wave = t >> 6, lane = t & 63;

    __shared__ float lh_sh[2][512];
    __shared__ float psum[2][4];

    for (int p = blockIdx.x; 2 * p < total; p += gridDim.x) {
        const int it0 = 2 * p;
        const int it1v = (2 * p + 1 < total);
        const uint32_t item0 = items[it0];
        const uint32_t item1 = it1v ? items[it0 + 1] : item0;

        int rowA = item0 >> 6, zA = item0 & 63;
        int bA = rowA / L_DIM, posA = rowA % L_DIM;
        int nA = zA >> 2, lkA = (zA >> 1) & 1, rkA = zA & 1;
        int lcA = level_off(nA) + posA, rcA = level_off(15 - nA) + posA + nA + 1;
        int rowB = item1 >> 6, zB = item1 & 63;
        int bB = rowB / L_DIM, posB = rowB % L_DIM;
        int nB = zB >> 2, lkB = (zB >> 1) & 1, rkB = zB & 1;
        int lcB = level_off(nB) + posB, rcB = level_off(15 - nB) + posB + nB + 1;

        const float* lhA = chart_h + ((size_t)(lkA * B_DIM + bA) * NCELLS + lcA) * SZ;
        const float* rhA = chart_h + ((size_t)(rkA * B_DIM + bA) * NCELLS + rcA) * SZ;
        const float* lhB = chart_h + ((size_t)(lkB * B_DIM + bB) * NCELLS + lcB) * SZ;
        const float* rhB = chart_h + ((size_t)(rkB * B_DIM + bB) * NCELLS + rcB) * SZ;

        __syncthreads();
        lh_sh[0][t] = lhA[t]; lh_sh[0][t + 256] = lhA[t + 256];
        lh_sh[1][t] = lhB[t]; lh_sh[1][t + 256] = lhB[t + 256];
        const float4 rA0 = *(const float4*)(rhA + lane * 8);
        const float4 rA1 = *(const float4*)(rhA + lane * 8 + 4);
        const float4 rB0 = *(const float4*)(rhB + lane * 8);
        const float4 rB1 = *(const float4*)(rhB + lane * 8 + 4);
        __syncthreads();

        const float* mb = mat + (size_t)(wave * 128) * 512 + lane * 8;
        float a00 = 0.f, a01 = 0.f, b00 = 0.f, b01 = 0.f;
        for (int e = 0; e < 128; e += 2) {
            const float4 m0 = *(const float4*)(mb + (size_t)(e + 0) * 512);
            const float4 m1 = *(const float4*)(mb + (size_t)(e + 0) * 512 + 4);
            const float4 m2 = *(const float4*)(mb + (size_t)(e + 1) * 512);
            const float4 m3 = *(const float4*)(mb + (size_t)(e + 1) * 512 + 4);
            const int eg = wave * 128 + e;
            const float lA0 = lh_sh[0][eg],     lB0 = lh_sh[1][eg];
            const float lA1 = lh_sh[0][eg + 1], lB1 = lh_sh[1][eg + 1];
            const float dA0 = m0.x*rA0.x + m0.y*rA0.y + m0.z*rA0.z + m0.w*rA0.w
                            + m1.x*rA1.x + m1.y*rA1.y + m1.z*rA1.z + m1.w*rA1.w;
            const float dB0 = m0.x*rB0.x + m0.y*rB0.y + m0.z*rB0.z + m0.w*rB0.w
                            + m1.x*rB1.x + m1.y*rB1.y + m1.z*rB1.z + m1.w*rB1.w;
            const float dA1 = m2.x*rA0.x + m2.y*rA0.y + m2.z*rA0.z + m2.w*rA0.w
                            + m3.x*rA1.x + m3.y*rA1.y + m3.z*rA1.z + m3.w*rA1.w;
            const float dB1 = m2.x*rB0.x + m2.y*rB0.y + m2.z*rB0.z + m2.w*rB0.w
                            + m3.x*rB1.x + m3.y*rB1.y + m3.z*rB1.z + m3.w*rB1.w;
            a00 += lA0 * dA0; a01 += lA1 * dA1;
            b00 += lB0 * dB0; b01 += lB1 * dB1;
        }
        float sA = a00 + a01, sB = b00 + b01;
#pragma unroll
        for (int o = 32; o > 0; o >>= 1) {
            sA += __shfl_down(sA, o);
            sB += __shfl_down(sB, o);
        }
        if (lane == 0) { psum[0][wave] = sA; psum[1][wave] = sB; }
        __syncthreads();
        if (t == 0) {
            const float lsA = chart_s[(size_t)(lkA * B_DIM + bA) * NCELLS + lcA];
            const float rsA = chart_s[(size_t)(rkA * B_DIM + bA) * NCELLS + rcA];
            exval[it0] = psum[0][0] + psum[0][1] + psum[0][2] + psum[0][3] + lsA + rsA;
            if (it1v) {
                const float lsB = chart_s[(size_t)(lkB * B_DIM + bB) * NCELLS + lcB];
                const float rsB = chart_s[(size_t)(rkB * B_DIM + bB) * NCELLS + rcB];
                exval[it0 + 1] = psum[1][0] + psum[1][1] + psum[1][2] + psum[1][3] + lsB + rsB;
            }
        }
    }
}

// ---------------------------------------------------------------------------
// K3b: per flagged row, pick exact top-2 (z-ascending list + strict '>'
// replicates jax lowest-index tie-break), emit outputs + gather X.
// ---------------------------------------------------------------------------
__global__ __launch_bounds__(256)
void refine_pick(const float* __restrict__ chart_h,
                 const uint32_t* __restrict__ items,
                 const int* __restrict__ rowbase,
                 const int* __restrict__ flags,
                 const float* __restrict__ exval,
                 uint16_t* __restrict__ X,
                 float* __restrict__ out)
{
    const int row = blockIdx.x;
    const int nc = flags[row];
    if (nc == 0) return;
    const int b = row / L_DIM, pos = row % L_DIM;
    const int t = threadIdx.x;

    __shared__ int top_z[2];

    if (t == 0) {
        const int base = rowbase[row];
        float v1 = -3.4e38f; int c1 = -1;
        for (int c = 0; c < nc; ++c) {
            const float v = exval[base + c];
            if (v > v1) { v1 = v; c1 = c; }
        }
        float v2 = -3.4e38f; int c2 = -1;
        for (int c = 0; c < nc; ++c) {
            if (c == c1) continue;
            const float v = exval[base + c];
            if (v > v2) { v2 = v; c2 = c; }
        }
        const int i1 = (int)(items[base + c1] & 63u);
        const int i2 = (int)(items[base + c2] & 63u);
        top_z[0] = i1; top_z[1] = i2;
        emit_outputs(row, i1, i2, v1, v2, out);
    }
    __syncthreads();
    gather_x(row, pos, b, top_z, chart_h, X, t);
}

// ---------------------------------------------------------------------------
// transpose_wc: WcT[o][i] = bf16(Wc[i][o])
// ---------------------------------------------------------------------------
__global__ __launch_bounds__(256)
void transpose_wc(const float* __restrict__ Wc, uint16_t* __restrict__ WcT)
{
    __shared__ float tbuf[64][65];
    const int i0 = blockIdx.x * 64;
    const int o0 = blockIdx.y * 64;
    const int c = threadIdx.x & 63, r4 = threadIdx.x >> 6;
    for (int rr = r4; rr < 64; rr += 4)
        tbuf[rr][c] = Wc[(size_t)(i0 + rr) * 512 + o0 + c];
    __syncthreads();
    for (int rr = r4; rr < 64; rr += 4)
        WcT[(size_t)(o0 + rr) * 1024 + i0 + c] = f2bf(tbuf[c][rr]);
}

// ---------------------------------------------------------------------------
// K4: H = tanh(X @ WcT^T + bc)  (bf16 in, f32 out)
// ---------------------------------------------------------------------------
typedef __bf16 bf16x8 __attribute__((ext_vector_type(8)));

__global__ __launch_bounds__(256, 2)
void gemm_compose(const uint16_t* __restrict__ A,
                  const uint16_t* __restrict__ Bm,
                  const float* __restrict__ bias,
                  float* __restrict__ C,
                  int M, int Nn, int Kk)
{
    __shared__ uint16_t As[128 * 64];
    __shared__ uint16_t Bs[128 * 64];

    const int tid  = threadIdx.x;
    const int wave = tid >> 6, lane = tid & 63;
    const int m0 = blockIdx.x * 128, n0 = blockIdx.y * 128;
    const int wm = (wave & 1) * 64, wn = (wave >> 1) * 64;
    const int col_l = lane & 15, quad = lane >> 4;
    const int lrow = lane >> 3;
    const int lcol = (lane & 7) * 8;

    f32x4 acc[4][4];
#pragma unroll
    for (int i = 0; i < 4; ++i)
#pragma unroll
        for (int j = 0; j < 4; ++j) acc[i][j] = (f32x4){0.f, 0.f, 0.f, 0.f};

    for (int k0 = 0; k0 < Kk; k0 += 64) {
        __syncthreads();
#pragma unroll
        for (int i = 0; i < 4; ++i) {
            const int q = wave * 4 + i;
            const int r = q * 8 + lrow;
            GLD16(A  + (size_t)(m0 + r) * Kk + k0 + lcol, (char*)As + q * 1024);
            GLD16(Bm + (size_t)(n0 + r) * Kk + k0 + lcol, (char*)Bs + q * 1024);
        }
        __syncthreads();
#pragma unroll
        for (int kk = 0; kk < 64; kk += 32) {
            bf16x8 af[4], bfr[4];
#pragma unroll
            for (int mi = 0; mi < 4; ++mi)
                af[mi] = *(const bf16x8*)&As[(wm + mi * 16 + col_l) * 64 + kk + quad * 8];
#pragma unroll
            for (int ni = 0; ni < 4; ++ni)
                bfr[ni] = *(const bf16x8*)&Bs[(wn + ni * 16 + col_l) * 64 + kk + quad * 8];
#pragma unroll
            for (int mi = 0; mi < 4; ++mi)
#pragma unroll
                for (int ni = 0; ni < 4; ++ni)
                    acc[mi][ni] = __builtin_amdgcn_mfma_f32_16x16x32_bf16(
                        af[mi], bfr[ni], acc[mi][ni], 0, 0, 0);
        }
    }

#pragma unroll
    for (int ni = 0; ni < 4; ++ni) {
        const int ncol = n0 + wn + ni * 16 + col_l;
        const float bv = bias[ncol];
#pragma unroll
        for (int mi = 0; mi < 4; ++mi) {
            const int mrow = m0 + wm + mi * 16 + quad * 4;
#pragma unroll
            for (int r = 0; r < 4; ++r)
                C[(size_t)(mrow + r) * Nn + ncol] = tanhf(acc[mi][ni][r] + bv);
        }
    }
}

// ---------------------------------------------------------------------------
// K5: unit-normalize H rows -> topk_h
// ---------------------------------------------------------------------------
__global__ __launch_bounds__(256)
void norm_rows(const float* __restrict__ H, float* __restrict__ out)
{
    const int row = blockIdx.x;
    const float* h = H + (size_t)row * SZ;
    const int t = threadIdx.x;
    const int wave = t >> 6, lane = t & 63;
    const float a = h[t], c = h[t + 256];
    float ss = a * a + c * c;
#pragma unroll
    for (int o = 32; o > 0; o >>= 1) ss += __shfl_down(ss, o);
    __shared__ float wsum[4];
    if (lane == 0) wsum[wave] = ss;
    __syncthreads();
    const float inv = rsqrtf(wsum[0] + wsum[1] + wsum[2] + wsum[3]);
    out[(size_t)row * SZ + t]       = a * inv;
    out[(size_t)row * SZ + t + 256] = c * inv;
}

// ---------------------------------------------------------------------------
extern "C" void kernel_launch(void* const* d_in, const int* in_sizes, int n_in,
                              void* d_out, int out_size, void* d_ws, size_t ws_size,
                              hipStream_t stream)
{
    const float* chart_h = (const float*)d_in[0];
    const float* chart_s = (const float*)d_in[1];
    const float* mat = (const float*)d_in[4];
    const float* Wc  = (const float*)d_in[5];
    const float* bc  = (const float*)d_in[6];
    float* out = (float*)d_out;

    // workspace (peak ~66.5 MB; proven ws >= 125.8 MB):
    //   T16   f16 [57856][512] @ 0            (59,244,544)  alive K1->K2
    //   MAT16 f16 [512][512]   @ 59,244,544   (   524,288)  dead after K1
    //   ITEMS u32[49152]       @ 59,768,832   (   196,608)
    //   EXVAL f32[49152]       @ 59,965,440   (   196,608)
    //   RBASE i32[1536]        @ 60,162,048   (     6,144)
    //   CNT   i32              @ 60,168,192   (       256)
    //   FLAGS i32[1536]        @ 60,168,448   (     6,144)
    //   X     bf16[3072][1024] @ 60,174,592   ( 6,291,456)
    //   WcT   bf16[512][1024]  @ 0            (reuses T16 region after K2)
    //   H     f32 [3072][512]  @ 1,048,576    (reuses T16 region after K2)
    char* ws = (char*)d_ws;
    _Float16* T16   = (_Float16*)ws;
    _Float16* MAT16 = (_Float16*)(ws + 59244544);
    uint32_t* ITEMS = (uint32_t*)(ws + 59768832);
    float*    EXVAL = (float*)(ws + 59965440);
    int*      RBASE = (int*)(ws + 60162048);
    int*      CNT   = (int*)(ws + 60168192);
    int*      FLAGS = (int*)(ws + 60168448);
    uint16_t* X     = (uint16_t*)(ws + 60174592);
    uint16_t* WcT   = (uint16_t*)ws;
    float*    H     = (float*)(ws + 1048576);

    hipMemsetAsync(CNT, 0, 4, stream);
    // P0: mat16 = f16(64*mat)  (128*2048 = 262,144 exact)
    prep_mat<<<dim3(128), 256, 0, stream>>>(mat, MAT16);
    // K1: T' = f16(16*chart_h) @ MAT16^T, no-LDS direct-fragment version
    gemm_fused<<<dim3(904), 256, 0, stream>>>(chart_h, MAT16, T16);
    // K2: cheap scores + top3 + candidate queue; outputs + X for clean rows
    score_topk<<<dim3(B_DIM * L_DIM), 256, 0, stream>>>(chart_h, T16, chart_s,
                                                        ITEMS, RBASE, CNT, FLAGS, X, out);
    // (T16/MAT16 dead from here; WcT/H overlay T16 region)
    transpose_wc<<<dim3(16, 8), 256, 0, stream>>>(Wc, WcT);
    // K3a: exact eval, block per item pair (mat shared within pair)
    refine_eval<<<dim3(1024), 256, 0, stream>>>(chart_h, chart_s, mat, ITEMS, CNT, EXVAL);
    // K3b: per-row exact top-2 + outputs + X
    refine_pick<<<dim3(B_DIM * L_DIM), 256, 0, stream>>>(chart_h, ITEMS, RBASE, FLAGS,
                                                         EXVAL, X, out);
    // K4: H = tanh(X @ WcT^T + bc)
    gemm_compose<<<dim3(24, 4), 256, 0, stream>>>(X, WcT, bc, H, 3072, 512, 1024);
    // K5: topk_h = H / ||H||
    norm_rows<<<dim3(3072), 256, 0, stream>>>(H, out);
}

// Round 5
// 341.354 us; speedup vs baseline: 1.0767x; 1.0767x over previous
//
#include <hip/hip_runtime.h>
#include <cstdint>
#include <cstddef>

// ---------------------------------------------------------------------------
// Problem constants (LEVEL=16, LENGTH=64, TOPK=2, SIZE=512, BATCH=32)
// Cheap path: f16 MFMA scores; rows with cheap top-2/3 gaps < DELTA=0.25 get
// exact f32 refinement over candidates {z: cheap[z] >= cheap_top2 - DELTA}.
//
// K1 history:
// r7: 64m x 512n tile, DMA-staged A(f32)+B(f16), 2-barrier, conflicted: 98us.
// r8/r9: fragment-order (conflict 7.4M->0) + A reg-stage: 122us (reg-stage
//     serialization cost > conflict saving ~7us).
// r10: LDS dbuf + __syncthreads: 122us (barrier drains vmcnt(0) every step).
// r11: no-LDS direct loads: 146us. VGPR_Count=128 == acc size: the 64x512
//     tile's 128-reg accumulator pins the budget; loads serialize. Same
//     acc also caps ALL variants at ~2 blocks/CU -> no drain overlap.
// r12: split N across blocks. Grid (2,904), tile 64m x 256n, acc[4][4]=64
//     regs -> 3 blocks/CU; LDS 24KB; per-step DMA 24KB. Keep r7's 2-barrier
//     DMA skeleton (fastest measured), fragment-order B (verified), A f32
//     DMA with XOR-swizzled source units (conflict-free f32 reads),
//     convert-on-read (r7's overlap behavior).
// ---------------------------------------------------------------------------
#define B_DIM   32
#define L_DIM   48
#define NCELLS  904
#define SZ      512
#define NEGF    (-1e8f)
#define DELTA   0.25f
#define MAXC    32          // max candidates per row kept (z-ascending)

// d_out layout (f32), outputs concatenated flat in return order
#define OFF_S   1572864
#define OFF_N   1575936
#define OFF_L   1579008
#define OFF_R   1582080

typedef _Float16  f16x8 __attribute__((ext_vector_type(8)));
typedef float     f32x4 __attribute__((ext_vector_type(4)));

static __device__ __forceinline__ uint16_t f2bf(float f) {
    uint32_t u = __builtin_bit_cast(uint32_t, f);
    u += 0x7fffu + ((u >> 16) & 1u);
    return (uint16_t)(u >> 16);
}

#define GLD16(gp, lp) __builtin_amdgcn_global_load_lds(                        \
        (__attribute__((address_space(1))) void*)(gp),                         \
        (__attribute__((address_space(3))) void*)(lp), 16, 0, 0)

static __device__ __forceinline__ int level_off(int n) {
    return n * 64 - (n * (n - 1)) / 2;
}

// ---------------------------------------------------------------------------
// P0: matf16 = f16(64*mat)  (tiny: 1MB read)
// ---------------------------------------------------------------------------
__global__ __launch_bounds__(256)
void prep_mat(const float* __restrict__ mat, _Float16* __restrict__ mat16)
{
    const size_t j = ((size_t)blockIdx.x * 256 + threadIdx.x) * 8;
    const float4 c = *(const float4*)(mat + j);
    const float4 d = *(const float4*)(mat + j + 4);
    f16x8 w;
    w[0]=(_Float16)(c.x*64.f); w[1]=(_Float16)(c.y*64.f);
    w[2]=(_Float16)(c.z*64.f); w[3]=(_Float16)(c.w*64.f);
    w[4]=(_Float16)(d.x*64.f); w[5]=(_Float16)(d.y*64.f);
    w[6]=(_Float16)(d.z*64.f); w[7]=(_Float16)(d.w*64.f);
    *(f16x8*)(mat16 + j) = w;
}

// ---------------------------------------------------------------------------
// K1: T'[m,e] = sum_d f16(16*A[m,d]) * B16[e,d].  Grid (2,904): x = n-half
// (256 cols), y = m-tile (64 rows). BK=32, 16 K-steps. 4 waves; wave w owns
// n-range n0+64w..+64, acc[4][4] (64 regs -> 3 blocks/CU). T' is 1024x true.
//
// LDS (24KB):
//   As32: f32 [64 rows][32 k], 128B rows, XOR-swizzled 16B units:
//     LDS[row][byte b] holds A[row][k0 + (b ^ ((row&7)<<4))/4 ...].
//     Staged by 8 GLD16 chunks (2/wave): chunk q rows q*8..+8, lane l ->
//     row q*8+(l>>3), source k-f32 = k0 + ((l&7)^(l>>3))*4  (source stays
//     within the row's 128B span -> same coalescing as linear).
//     Read (mi,h): byte = mi*2048 + col_l*128 + ((quad*32+h*16)^((col_l&7)<<4))
//     -> all 8 bank-quads hit uniformly = conflict-free minimum.
//   Bs: f16 fragment-order (r8-verified): chunk q (16 n-rows), lane l sources
//     Bm[n0+q*16+(l&15)][k0+(l>>4)*8..+8]; wave reads chunk (wave*4+ni) at
//     Bs[(wave*4+ni)*512 + lane*8] (lane-linear).
// Loop: { sync; issue 6 GLD16/wave; sync; convert A + 16 MFMA }  (r7 skeleton)
// ---------------------------------------------------------------------------
__global__ __launch_bounds__(256, 3)
void gemm_fused(const float* __restrict__ A,        // chart_h f32 [57856][512]
                const _Float16* __restrict__ Bm,    // mat16 [512][512]
                _Float16* __restrict__ C)           // T16 [57856][512]
{
    __shared__ float    As32[64 * 32];   //  8 KB
    __shared__ _Float16 Bs[256 * 32];    // 16 KB

    const int t = threadIdx.x;
    const int wave = t >> 6, lane = t & 63;
    const int n0 = blockIdx.x * 256;
    const int m0 = blockIdx.y * 64;
    const int col_l = lane & 15, quad = lane >> 4;

    f32x4 acc[4][4];
#pragma unroll
    for (int i = 0; i < 4; ++i)
#pragma unroll
        for (int j = 0; j < 4; ++j) acc[i][j] = (f32x4){0.f, 0.f, 0.f, 0.f};

    const int arow = lane >> 3;                    // 0..7 within A chunk
    const int aswz = ((lane & 7) ^ arow) * 4;      // source k-offset (f32)
    const int asw_rd = (col_l & 7) << 4;           // read-side XOR (bytes)

    for (int ks = 0; ks < 16; ++ks) {
        const int k0 = ks * 32;
        __syncthreads();                           // prev compute done
        // A: 8 chunks of 1KB (8 rows x 128B), 2 per wave, swizzled source
#pragma unroll
        for (int i = 0; i < 2; ++i) {
            const int q = wave * 2 + i;
            GLD16(A + (size_t)(m0 + q * 8 + arow) * 512 + k0 + aswz,
                  (char*)As32 + q * 1024);
        }
        // B: 16 chunks of 1KB, 4 per wave, fragment-order source
#pragma unroll
        for (int i = 0; i < 4; ++i) {
            const int q = wave * 4 + i;
            GLD16(Bm + (size_t)(n0 + q * 16 + col_l) * 512 + k0 + quad * 8,
                  (char*)Bs + q * 1024);
        }
        __syncthreads();                           // DMAs arrived

        // A fragments: swizzled f32 reads, convert x16 -> f16 (overlaps MFMA)
        f16x8 af[4];
#pragma unroll
        for (int mi = 0; mi < 4; ++mi) {
            const char* rb = (const char*)As32 + mi * 2048 + col_l * 128;
            const f32x4 p0 = *(const f32x4*)(rb + ((quad * 32 +  0) ^ asw_rd));
            const f32x4 p1 = *(const f32x4*)(rb + ((quad * 32 + 16) ^ asw_rd));
#pragma unroll
            for (int j = 0; j < 4; ++j) {
                af[mi][j]     = (_Float16)(p0[j] * 16.f);
                af[mi][j + 4] = (_Float16)(p1[j] * 16.f);
            }
        }
#pragma unroll
        for (int ni = 0; ni < 4; ++ni) {
            const f16x8 bf = *(const f16x8*)&Bs[(wave * 4 + ni) * 512 + lane * 8];
#pragma unroll
            for (int mi = 0; mi < 4; ++mi)
                acc[mi][ni] = __builtin_amdgcn_mfma_f32_16x16x32_f16(
                    af[mi], bf, acc[mi][ni], 0, 0, 0);
        }
    }

    // epilogue: C/D layout col=lane&15, row=quad*4+reg
#pragma unroll
    for (int ni = 0; ni < 4; ++ni) {
        const int ncol = n0 + wave * 64 + ni * 16 + col_l;
#pragma unroll
        for (int mi = 0; mi < 4; ++mi) {
            const int mrow = m0 + mi * 16 + quad * 4;
#pragma unroll
            for (int r = 0; r < 4; ++r)
                C[(size_t)(mrow + r) * 512 + ncol] = (_Float16)acc[mi][ni][r];
        }
    }
}

// ---------------------------------------------------------------------------
// shared epilogue helpers
// ---------------------------------------------------------------------------
static __device__ __forceinline__ void emit_outputs(
    int row, int i1, int i2, float v1, float v2, float* out)
{
    out[OFF_S + row * 2 + 0] = v1;
    out[OFF_S + row * 2 + 1] = v2;
    out[OFF_N + row * 2 + 0] = (float)(i1 >> 2);
    out[OFF_N + row * 2 + 1] = (float)(i2 >> 2);
    out[OFF_L + row * 2 + 0] = (float)((i1 >> 1) & 1);
    out[OFF_L + row * 2 + 1] = (float)((i2 >> 1) & 1);
    out[OFF_R + row * 2 + 0] = (float)(i1 & 1);
    out[OFF_R + row * 2 + 1] = (float)(i2 & 1);
}

static __device__ __forceinline__ void gather_x(
    int row, int pos, int b, const int* top_z,
    const float* __restrict__ chart_h, uint16_t* __restrict__ X, int tid)
{
#pragma unroll
    for (int kq = 0; kq < 2; ++kq) {
        const int z = top_z[kq];
        const int n = z >> 2, lk = (z >> 1) & 1, rk = z & 1;
        const int lcell = level_off(n) + pos;
        const int rcell = level_off(15 - n) + pos + n + 1;
        const float* srcl = chart_h + ((size_t)(lk * B_DIM + b) * NCELLS + lcell) * SZ;
        const float* srcr = chart_h + ((size_t)(rk * B_DIM + b) * NCELLS + rcell) * SZ;
        uint16_t* dst = X + ((size_t)row * 2 + kq) * 1024;
        const int e = tid * 2;
        const float2 a = *(const float2*)(srcl + e);
        const float2 c = *(const float2*)(srcr + e);
        *(uint32_t*)(dst + e)       = (uint32_t)f2bf(a.x) | ((uint32_t)f2bf(a.y) << 16);
        *(uint32_t*)(dst + 512 + e) = (uint32_t)f2bf(c.x) | ((uint32_t)f2bf(c.y) << 16);
    }
}

// ---------------------------------------------------------------------------
// K2: cheap scores (lh f32 x T16 f16), top-3, near-tie flagging + candidate
// queue (ballot compaction). Clean rows emit outputs + gather X here.
// ---------------------------------------------------------------------------
__global__ __launch_bounds__(256)
void score_topk(const float* __restrict__ chart_h,   // f32
                const _Float16* __restrict__ T16,    // x1024
                const float* __restrict__ chart_s,
                uint32_t* __restrict__ items,        // queue entries (row<<6|z)
                int* __restrict__ rowbase,           // [1536]
                int* __restrict__ counter,           // 1 int, pre-zeroed
                int* __restrict__ flags,             // [1536]: nc (0 = clean)
                uint16_t* __restrict__ X,
                float* __restrict__ out)
{
    const int b   = blockIdx.x / L_DIM;
    const int pos = blockIdx.x % L_DIM;
    const int row = blockIdx.x;
    const int wave = threadIdx.x >> 6, lane = threadIdx.x & 63;

    __shared__ float s_sh[64];
    __shared__ int top_z[2];
    __shared__ int flag_sh;

#pragma unroll
    for (int ni = 0; ni < 4; ++ni) {
        const int n = wave * 4 + ni;
        const int lcell = level_off(n) + pos;
        const int rcell = level_off(15 - n) + pos + n + 1;

        const float* lp0 = chart_h + ((size_t)(0 * B_DIM + b) * NCELLS + lcell) * SZ + lane * 8;
        const float* lp1 = chart_h + ((size_t)(1 * B_DIM + b) * NCELLS + lcell) * SZ + lane * 8;
        const float4 l0a = *(const float4*)lp0, l0b = *(const float4*)(lp0 + 4);
        const float4 l1a = *(const float4*)lp1, l1b = *(const float4*)(lp1 + 4);
        const f16x8 t0 = *(const f16x8*)(T16 + ((size_t)(0 * B_DIM + b) * NCELLS + rcell) * SZ + lane * 8);
        const f16x8 t1 = *(const f16x8*)(T16 + ((size_t)(1 * B_DIM + b) * NCELLS + rcell) * SZ + lane * 8);

        float l0[8] = {l0a.x, l0a.y, l0a.z, l0a.w, l0b.x, l0b.y, l0b.z, l0b.w};
        float l1[8] = {l1a.x, l1a.y, l1a.z, l1a.w, l1b.x, l1b.y, l1b.z, l1b.w};

        float d00 = 0.f, d01 = 0.f, d10 = 0.f, d11 = 0.f;
#pragma unroll
        for (int j = 0; j < 8; ++j) {
            const float c0 = (float)t0[j], c1 = (float)t1[j];
            d00 += l0[j] * c0; d01 += l0[j] * c1;
            d10 += l1[j] * c0; d11 += l1[j] * c1;
        }
#pragma unroll
        for (int o = 32; o > 0; o >>= 1) {
            d00 += __shfl_down(d00, o);
            d01 += __shfl_down(d01, o);
            d10 += __shfl_down(d10, o);
            d11 += __shfl_down(d11, o);
        }
        if (lane == 0) {
            const float ls0 = chart_s[(size_t)(0 * B_DIM + b) * NCELLS + lcell];
            const float ls1 = chart_s[(size_t)(1 * B_DIM + b) * NCELLS + lcell];
            const float rs0 = chart_s[(size_t)(0 * B_DIM + b) * NCELLS + rcell];
            const float rs1 = chart_s[(size_t)(1 * B_DIM + b) * NCELLS + rcell];
            const float inv = 1.0f / 1024.0f;        // undo x1024 on T'
            s_sh[n * 4 + 0] = d00 * inv + ls0 + rs0;
            s_sh[n * 4 + 1] = d01 * inv + ls0 + rs1;
            s_sh[n * 4 + 2] = d10 * inv + ls1 + rs0;
            s_sh[n * 4 + 3] = d11 * inv + ls1 + rs1;
        }
    }
    __syncthreads();

    if (threadIdx.x < 64) {
        float v = s_sh[lane];
        if (lane == 2 || lane == 3) v = NEGF;        // penalty mask
        float v1 = v; int i1 = lane;
#pragma unroll
        for (int o = 32; o > 0; o >>= 1) {
            float ov = __shfl_down(v1, o);
            int   oi = __shfl_down(i1, o);
            if (ov > v1 || (ov == v1 && oi < i1)) { v1 = ov; i1 = oi; }
        }
        v1 = __shfl(v1, 0); i1 = __shfl(i1, 0);
        float v2 = (lane == i1) ? -3.4e38f : v; int i2 = lane;
#pragma unroll
        for (int o = 32; o > 0; o >>= 1) {
            float ov = __shfl_down(v2, o);
            int   oi = __shfl_down(i2, o);
            if (ov > v2 || (ov == v2 && oi < i2)) { v2 = ov; i2 = oi; }
        }
        v2 = __shfl(v2, 0); i2 = __shfl(i2, 0);
        float v3 = (lane == i1 || lane == i2) ? -3.4e38f : v;
#pragma unroll
        for (int o = 32; o > 0; o >>= 1) {
            const float ov = __shfl_down(v3, o);
            if (ov > v3) v3 = ov;
        }
        v3 = __shfl(v3, 0);

        const int f = (v1 - v2 < DELTA) || (v2 - v3 < DELTA);
        const bool cand = (v >= v2 - DELTA);
        const unsigned long long mask = __ballot(cand);
        const int nc_full = __popcll(mask);
        const int nc = nc_full < MAXC ? nc_full : MAXC;
        int base = 0;
        if (lane == 0) {
            flags[row] = f ? nc : 0;
            flag_sh = f;
            if (f) base = atomicAdd(counter, nc);
            rowbase[row] = base;
            top_z[0] = i1; top_z[1] = i2;
            if (!f) emit_outputs(row, i1, i2, v1, v2, out);
        }
        base = __shfl(base, 0);
        if (f && cand) {
            const int rank = __popcll(mask & ((1ull << lane) - 1ull));
            if (rank < MAXC) items[base + rank] = ((uint32_t)row << 6) | (uint32_t)lane;
        }
    }
    __syncthreads();

    if (!flag_sh)
        gather_x(row, pos, b, top_z, chart_h, X, threadIdx.x);
}

// ---------------------------------------------------------------------------
// K3a: exact f32 eval, block per ITEM PAIR (both items share the 1MB mat
// sweep). Waves split the e-range; lane owns rh[8*lane..+8) in regs.
// ---------------------------------------------------------------------------
__global__ __launch_bounds__(256)
void refine_eval(const float* __restrict__ chart_h,
                 const float* __restrict__ chart_s,
                 const float* __restrict__ mat,
                 const uint32_t* __restrict__ items,
                 const int* __restrict__ counter,
                 float* __restrict__ exval)
{
    const int total = *counter;
    const int t = threadIdx.x;
    const int wave = t >> 6, lane = t & 63;

    __shared__ float lh_sh[2][512];
    __shared__ float psum[2][4];

    for (int p = blockIdx.x; 2 * p < total; p += gridDim.x) {
        const int it0 = 2 * p;
        const int it1v = (2 * p + 1 < total);
        const uint32_t item0 = items[it0];
        const uint32_t item1 = it1v ? items[it0 + 1] : item0;

        int rowA = item0 >> 6, zA = item0 & 63;
        int bA = rowA / L_DIM, posA = rowA % L_DIM;
        int nA = zA >> 2, lkA = (zA >> 1) & 1, rkA = zA & 1;
        int lcA = level_off(nA) + posA, rcA = level_off(15 - nA) + posA + nA + 1;
        int rowB = item1 >> 6, zB = item1 & 63;
        int bB = rowB / L_DIM, posB = rowB % L_DIM;
        int nB = zB >> 2, lkB = (zB >> 1) & 1, rkB = zB & 1;
        int lcB = level_off(nB) + posB, rcB = level_off(15 - nB) + posB + nB + 1;

        const float* lhA = chart_h + ((size_t)(lkA * B_DIM + bA) * NCELLS + lcA) * SZ;
        const float* rhA = chart_h + ((size_t)(rkA * B_DIM + bA) * NCELLS + rcA) * SZ;
        const float* lhB = chart_h + ((size_t)(lkB * B_DIM + bB) * NCELLS + lcB) * SZ;
        const float* rhB = chart_h + ((size_t)(rkB * B_DIM + bB) * NCELLS + rcB) * SZ;

        __syncthreads();
        lh_sh[0][t] = lhA[t]; lh_sh[0][t + 256] = lhA[t + 256];
        lh_sh[1][t] = lhB[t]; lh_sh[1][t + 256] = lhB[t + 256];
        const float4 rA0 = *(const float4*)(rhA + lane * 8);
        const float4 rA1 = *(const float4*)(rhA + lane * 8 + 4);
        const float4 rB0 = *(const float4*)(rhB + lane * 8);
        const float4 rB1 = *(const float4*)(rhB + lane * 8 + 4);
        __syncthreads();

        const float* mb = mat + (size_t)(wave * 128) * 512 + lane * 8;
        float a00 = 0.f, a01 = 0.f, b00 = 0.f, b01 = 0.f;
        for (int e = 0; e < 128; e += 2) {
            const float4 m0 = *(const float4*)(mb + (size_t)(e + 0) * 512);
            const float4 m1 = *(const float4*)(mb + (size_t)(e + 0) * 512 + 4);
            const float4 m2 = *(const float4*)(mb + (size_t)(e + 1) * 512);
            const float4 m3 = *(const float4*)(mb + (size_t)(e + 1) * 512 + 4);
            const int eg = wave * 128 + e;
            const float lA0 = lh_sh[0][eg],     lB0 = lh_sh[1][eg];
            const float lA1 = lh_sh[0][eg + 1], lB1 = lh_sh[1][eg + 1];
            const float dA0 = m0.x*rA0.x + m0.y*rA0.y + m0.z*rA0.z + m0.w*rA0.w
                            + m1.x*rA1.x + m1.y*rA1.y + m1.z*rA1.z + m1.w*rA1.w;
            const float dB0 = m0.x*rB0.x + m0.y*rB0.y + m0.z*rB0.z + m0.w*rB0.w
                            + m1.x*rB1.x + m1.y*rB1.y + m1.z*rB1.z + m1.w*rB1.w;
            const float dA1 = m2.x*rA0.x + m2.y*rA0.y + m2.z*rA0.z + m2.w*rA0.w
                            + m3.x*rA1.x + m3.y*rA1.y + m3.z*rA1.z + m3.w*rA1.w;
            const float dB1 = m2.x*rB0.x + m2.y*rB0.y + m2.z*rB0.z + m2.w*rB0.w
                            + m3.x*rB1.x + m3.y*rB1.y + m3.z*rB1.z + m3.w*rB1.w;
            a00 += lA0 * dA0; a01 += lA1 * dA1;
            b00 += lB0 * dB0; b01 += lB1 * dB1;
        }
        float sA = a00 + a01, sB = b00 + b01;
#pragma unroll
        for (int o = 32; o > 0; o >>= 1) {
            sA += __shfl_down(sA, o);
            sB += __shfl_down(sB, o);
        }
        if (lane == 0) { psum[0][wave] = sA; psum[1][wave] = sB; }
        __syncthreads();
        if (t == 0) {
            const float lsA = chart_s[(size_t)(lkA * B_DIM + bA) * NCELLS + lcA];
            const float rsA = chart_s[(size_t)(rkA * B_DIM + bA) * NCELLS + rcA];
            exval[it0] = psum[0][0] + psum[0][1] + psum[0][2] + psum[0][3] + lsA + rsA;
            if (it1v) {
                const float lsB = chart_s[(size_t)(lkB * B_DIM + bB) * NCELLS + lcB];
                const float rsB = chart_s[(size_t)(rkB * B_DIM + bB) * NCELLS + rcB];
                exval[it0 + 1] = psum[1][0] + psum[1][1] + psum[1][2] + psum[1][3] + lsB + rsB;
            }
        }
    }
}

// ---------------------------------------------------------------------------
// K3b: per flagged row, pick exact top-2 (z-ascending list + strict '>'
// replicates jax lowest-index tie-break), emit outputs + gather X.
// ---------------------------------------------------------------------------
__global__ __launch_bounds__(256)
void refine_pick(const float* __restrict__ chart_h,
                 const uint32_t* __restrict__ items,
                 const int* __restrict__ rowbase,
                 const int* __restrict__ flags,
                 const float* __restrict__ exval,
                 uint16_t* __restrict__ X,
                 float* __restrict__ out)
{
    const int row = blockIdx.x;
    const int nc = flags[row];
    if (nc == 0) return;
    const int b = row / L_DIM, pos = row % L_DIM;
    const int t = threadIdx.x;

    __shared__ int top_z[2];

    if (t == 0) {
        const int base = rowbase[row];
        float v1 = -3.4e38f; int c1 = -1;
        for (int c = 0; c < nc; ++c) {
            const float v = exval[base + c];
            if (v > v1) { v1 = v; c1 = c; }
        }
        float v2 = -3.4e38f; int c2 = -1;
        for (int c = 0; c < nc; ++c) {
            if (c == c1) continue;
            const float v = exval[base + c];
            if (v > v2) { v2 = v; c2 = c; }
        }
        const int i1 = (int)(items[base + c1] & 63u);
        const int i2 = (int)(items[base + c2] & 63u);
        top_z[0] = i1; top_z[1] = i2;
        emit_outputs(row, i1, i2, v1, v2, out);
    }
    __syncthreads();
    gather_x(row, pos, b, top_z, chart_h, X, t);
}

// ---------------------------------------------------------------------------
// transpose_wc: WcT[o][i] = bf16(Wc[i][o])
// ---------------------------------------------------------------------------
__global__ __launch_bounds__(256)
void transpose_wc(const float* __restrict__ Wc, uint16_t* __restrict__ WcT)
{
    __shared__ float tbuf[64][65];
    const int i0 = blockIdx.x * 64;
    const int o0 = blockIdx.y * 64;
    const int c = threadIdx.x & 63, r4 = threadIdx.x >> 6;
    for (int rr = r4; rr < 64; rr += 4)
        tbuf[rr][c] = Wc[(size_t)(i0 + rr) * 512 + o0 + c];
    __syncthreads();
    for (int rr = r4; rr < 64; rr += 4)
        WcT[(size_t)(o0 + rr) * 1024 + i0 + c] = f2bf(tbuf[c][rr]);
}

// ---------------------------------------------------------------------------
// K4: H = tanh(X @ WcT^T + bc)  (bf16 in, f32 out)
// ---------------------------------------------------------------------------
typedef __bf16 bf16x8 __attribute__((ext_vector_type(8)));

__global__ __launch_bounds__(256, 2)
void gemm_compose(const uint16_t* __restrict__ A,
                  const uint16_t* __restrict__ Bm,
                  const float* __restrict__ bias,
                  float* __restrict__ C,
                  int M, int Nn, int Kk)
{
    __shared__ uint16_t As[128 * 64];
    __shared__ uint16_t Bs[128 * 64];

    const int tid  = threadIdx.x;
    const int wave = tid >> 6, lane = tid & 63;
    const int m0 = blockIdx.x * 128, n0 = blockIdx.y * 128;
    const int wm = (wave & 1) * 64, wn = (wave >> 1) * 64;
    const int col_l = lane & 15, quad = lane >> 4;
    const int lrow = lane >> 3;
    const int lcol = (lane & 7) * 8;

    f32x4 acc[4][4];
#pragma unroll
    for (int i = 0; i < 4; ++i)
#pragma unroll
        for (int j = 0; j < 4; ++j) acc[i][j] = (f32x4){0.f, 0.f, 0.f, 0.f};

    for (int k0 = 0; k0 < Kk; k0 += 64) {
        __syncthreads();
#pragma unroll
        for (int i = 0; i < 4; ++i) {
            const int q = wave * 4 + i;
            const int r = q * 8 + lrow;
            GLD16(A  + (size_t)(m0 + r) * Kk + k0 + lcol, (char*)As + q * 1024);
            GLD16(Bm + (size_t)(n0 + r) * Kk + k0 + lcol, (char*)Bs + q * 1024);
        }
        __syncthreads();
#pragma unroll
        for (int kk = 0; kk < 64; kk += 32) {
            bf16x8 af[4], bfr[4];
#pragma unroll
            for (int mi = 0; mi < 4; ++mi)
                af[mi] = *(const bf16x8*)&As[(wm + mi * 16 + col_l) * 64 + kk + quad * 8];
#pragma unroll
            for (int ni = 0; ni < 4; ++ni)
                bfr[ni] = *(const bf16x8*)&Bs[(wn + ni * 16 + col_l) * 64 + kk + quad * 8];
#pragma unroll
            for (int mi = 0; mi < 4; ++mi)
#pragma unroll
                for (int ni = 0; ni < 4; ++ni)
                    acc[mi][ni] = __builtin_amdgcn_mfma_f32_16x16x32_bf16(
                        af[mi], bfr[ni], acc[mi][ni], 0, 0, 0);
        }
    }

#pragma unroll
    for (int ni = 0; ni < 4; ++ni) {
        const int ncol = n0 + wn + ni * 16 + col_l;
        const float bv = bias[ncol];
#pragma unroll
        for (int mi = 0; mi < 4; ++mi) {
            const int mrow = m0 + wm + mi * 16 + quad * 4;
#pragma unroll
            for (int r = 0; r < 4; ++r)
                C[(size_t)(mrow + r) * Nn + ncol] = tanhf(acc[mi][ni][r] + bv);
        }
    }
}

// ---------------------------------------------------------------------------
// K5: unit-normalize H rows -> topk_h
// ---------------------------------------------------------------------------
__global__ __launch_bounds__(256)
void norm_rows(const float* __restrict__ H, float* __restrict__ out)
{
    const int row = blockIdx.x;
    const float* h = H + (size_t)row * SZ;
    const int t = threadIdx.x;
    const int wave = t >> 6, lane = t & 63;
    const float a = h[t], c = h[t + 256];
    float ss = a * a + c * c;
#pragma unroll
    for (int o = 32; o > 0; o >>= 1) ss += __shfl_down(ss, o);
    __shared__ float wsum[4];
    if (lane == 0) wsum[wave] = ss;
    __syncthreads();
    const float inv = rsqrtf(wsum[0] + wsum[1] + wsum[2] + wsum[3]);
    out[(size_t)row * SZ + t]       = a * inv;
    out[(size_t)row * SZ + t + 256] = c * inv;
}

// ---------------------------------------------------------------------------
extern "C" void kernel_launch(void* const* d_in, const int* in_sizes, int n_in,
                              void* d_out, int out_size, void* d_ws, size_t ws_size,
                              hipStream_t stream)
{
    const float* chart_h = (const float*)d_in[0];
    const float* chart_s = (const float*)d_in[1];
    const float* mat = (const float*)d_in[4];
    const float* Wc  = (const float*)d_in[5];
    const float* bc  = (const float*)d_in[6];
    float* out = (float*)d_out;

    // workspace (peak ~66.5 MB; proven ws >= 125.8 MB):
    //   T16   f16 [57856][512] @ 0            (59,244,544)  alive K1->K2
    //   MAT16 f16 [512][512]   @ 59,244,544   (   524,288)  dead after K1
    //   ITEMS u32[49152]       @ 59,768,832   (   196,608)
    //   EXVAL f32[49152]       @ 59,965,440   (   196,608)
    //   RBASE i32[1536]        @ 60,162,048   (     6,144)
    //   CNT   i32              @ 60,168,192   (       256)
    //   FLAGS i32[1536]        @ 60,168,448   (     6,144)
    //   X     bf16[3072][1024] @ 60,174,592   ( 6,291,456)
    //   WcT   bf16[512][1024]  @ 0            (reuses T16 region after K2)
    //   H     f32 [3072][512]  @ 1,048,576    (reuses T16 region after K2)
    char* ws = (char*)d_ws;
    _Float16* T16   = (_Float16*)ws;
    _Float16* MAT16 = (_Float16*)(ws + 59244544);
    uint32_t* ITEMS = (uint32_t*)(ws + 59768832);
    float*    EXVAL = (float*)(ws + 59965440);
    int*      RBASE = (int*)(ws + 60162048);
    int*      CNT   = (int*)(ws + 60168192);
    int*      FLAGS = (int*)(ws + 60168448);
    uint16_t* X     = (uint16_t*)(ws + 60174592);
    uint16_t* WcT   = (uint16_t*)ws;
    float*    H     = (float*)(ws + 1048576);

    hipMemsetAsync(CNT, 0, 4, stream);
    // P0: mat16 = f16(64*mat)  (128*2048 = 262,144 exact)
    prep_mat<<<dim3(128), 256, 0, stream>>>(mat, MAT16);
    // K1: T' = f16(16*chart_h) @ MAT16^T, split-N (x = n-half), 3 blocks/CU
    gemm_fused<<<dim3(2, 904), 256, 0, stream>>>(chart_h, MAT16, T16);
    // K2: cheap scores + top3 + candidate queue; outputs + X for clean rows
    score_topk<<<dim3(B_DIM * L_DIM), 256, 0, stream>>>(chart_h, T16, chart_s,
                                                        ITEMS, RBASE, CNT, FLAGS, X, out);
    // (T16/MAT16 dead from here; WcT/H overlay T16 region)
    transpose_wc<<<dim3(16, 8), 256, 0, stream>>>(Wc, WcT);
    // K3a: exact eval, block per item pair (mat shared within pair)
    refine_eval<<<dim3(1024), 256, 0, stream>>>(chart_h, chart_s, mat, ITEMS, CNT, EXVAL);
    // K3b: per-row exact top-2 + outputs + X
    refine_pick<<<dim3(B_DIM * L_DIM), 256, 0, stream>>>(chart_h, ITEMS, RBASE, FLAGS,
                                                         EXVAL, X, out);
    // K4: H = tanh(X @ WcT^T + bc)
    gemm_compose<<<dim3(24, 4), 256, 0, stream>>>(X, WcT, bc, H, 3072, 512, 1024);
    // K5: topk_h = H / ||H||
    norm_rows<<<dim3(3072), 256, 0, stream>>>(H, out);
}

// Round 6
// 315.354 us; speedup vs baseline: 1.1655x; 1.0824x over previous
//
#include <hip/hip_runtime.h>
#include <cstdint>
#include <cstddef>

// ---------------------------------------------------------------------------
// Problem constants (LEVEL=16, LENGTH=64, TOPK=2, SIZE=512, BATCH=32)
// Cheap path: f16 MFMA scores; rows with cheap top-2/3 gaps < DELTA=0.25 get
// exact f32 refinement over candidates {z: cheap[z] >= cheap_top2 - DELTA}.
//
// K1 history:
// r7:  64m x 512n, DMA-staged, 2-barrier, conflicted: 98us.
// r8/r9: fragment-order LDS (conflicts 7.4M->0): 122us.
// r10: LDS dbuf + __syncthreads: 122us (barrier drains vmcnt(0) each step).
// r11: no-LDS direct: 146us (VGPR=128 acc pins budget).
// r12: split-N, acc=64, 3 blocks/CU, occupancy 17->34%: 120us. UNCHANGED.
// Cross-round analysis: ALL variants deliver ~10 B/cy/CU through
// global_load_lds (7670cy per 72KB step-window), vs the m97 reference's
// ~65 B/cy/CU with the IDENTICAL 2-barrier drain structure. The one
// difference: our GLD16 sources were cross-row gathers (16x64B segments
// over 16-32KB); m97's are contiguous 1KB bursts. The DMA path is the
// bottleneck and it punishes scattered sources ~7x.
// r13: contiguous sources everywhere. prep_mat PRE-PACKS mat16 into
// fragment-chunk order (chunk c = ksub*32+q is exactly one GLD16's 1KB,
// lane-linear). A is reg-staged f16 (vector loads issued first -> cvt waits
// vmcnt<=8, overlapping B drain). BK=64 (8 steps, half the drains).
// k-stagger per block decorrelates same-address L2 reads across CUs.
// ---------------------------------------------------------------------------
#define B_DIM   32
#define L_DIM   48
#define NCELLS  904
#define SZ      512
#define NEGF    (-1e8f)
#define DELTA   0.25f
#define MAXC    32          // max candidates per row kept (z-ascending)

// d_out layout (f32), outputs concatenated flat in return order
#define OFF_S   1572864
#define OFF_N   1575936
#define OFF_L   1579008
#define OFF_R   1582080

typedef _Float16  f16x8 __attribute__((ext_vector_type(8)));
typedef float     f32x4 __attribute__((ext_vector_type(4)));

static __device__ __forceinline__ uint16_t f2bf(float f) {
    uint32_t u = __builtin_bit_cast(uint32_t, f);
    u += 0x7fffu + ((u >> 16) & 1u);
    return (uint16_t)(u >> 16);
}

#define GLD16(gp, lp) __builtin_amdgcn_global_load_lds(                        \
        (__attribute__((address_space(1))) void*)(gp),                         \
        (__attribute__((address_space(3))) void*)(lp), 16, 0, 0)

static __device__ __forceinline__ int level_off(int n) {
    return n * 64 - (n * (n - 1)) / 2;
}

// ---------------------------------------------------------------------------
// P0: pack mat into fragment-chunk order, f16(64*mat).
// Chunk c = ksub*32 + q (ksub=k/32 in 0..15, q=n/16 in 0..31), 1KB each:
//   P[c*512 + lane*8 + j] = f16(64 * mat[16q + (lane&15)][32*ksub + (lane>>4)*8 + j])
// One GLD16 of chunk c delivers exactly the fragment bytes lane-linear.
// ---------------------------------------------------------------------------
__global__ __launch_bounds__(256)
void prep_mat(const float* __restrict__ mat, _Float16* __restrict__ P)
{
    const int tg   = blockIdx.x * 256 + threadIdx.x;   // 0..32767
    const int c    = tg >> 6, lane = tg & 63;
    const int srow = 16 * (c & 31) + (lane & 15);
    const int scol = 32 * (c >> 5) + (lane >> 4) * 8;
    const float4 a = *(const float4*)(mat + (size_t)srow * 512 + scol);
    const float4 b = *(const float4*)(mat + (size_t)srow * 512 + scol + 4);
    f16x8 w;
    w[0]=(_Float16)(a.x*64.f); w[1]=(_Float16)(a.y*64.f);
    w[2]=(_Float16)(a.z*64.f); w[3]=(_Float16)(a.w*64.f);
    w[4]=(_Float16)(b.x*64.f); w[5]=(_Float16)(b.y*64.f);
    w[6]=(_Float16)(b.z*64.f); w[7]=(_Float16)(b.w*64.f);
    *(f16x8*)(P + (size_t)tg * 8) = w;
}

// ---------------------------------------------------------------------------
// K1: T'[m,e] = sum_d f16(16*A[m,d]) * f16(64*mat[e,d]).  Grid (2,904):
// x = n-half (256 cols), y = m-tile (64 rows). BK=64, 8 K-steps (k-order
// staggered per block; accumulation order only). 4 waves; wave w owns
// n-range n0+64w..+64, acc[4][4]. T' is 1024x the true value.
//
// LDS (40KB), ALL accesses lane-linear (conflict-free):
//   As16: 8 chunks of 1KB; chunk (kki*4+mi) holds A-fragment (mi, kk=32kki).
//     Reg-staged: thread (w,lane) handles chunks 2w,2w+1; plain f32x4 loads
//     (issued FIRST -> cvt waits vmcnt<=8 only) -> x16 -> f16 -> ds_write.
//   Bs: 32 chunks of 1KB via GLD16 from packed P, source CONTIGUOUS.
//     chunk idx = kki*16+i  <- P chunk c = (kse*2+kki)*32 + n0/16 + i.
// Loop: { sync; A-loads; B-GLD16 x8/wave; cvt+ds_write; sync; 32 MFMA }.
// ---------------------------------------------------------------------------
__global__ __launch_bounds__(256, 3)
void gemm_fused(const float* __restrict__ A,        // chart_h f32 [57856][512]
                const _Float16* __restrict__ P,     // packed mat16 [512][1KB]
                _Float16* __restrict__ C)           // T16 [57856][512]
{
    __shared__ _Float16 As16[8 * 512];    //  8 KB
    __shared__ _Float16 Bs[32 * 512];     // 32 KB

    const int t = threadIdx.x;
    const int wave = t >> 6, lane = t & 63;
    const int n0 = blockIdx.x * 256;
    const int nq = n0 >> 4;
    const int m0 = blockIdx.y * 64;
    const int col_l = lane & 15, quad = lane >> 4;
    const int stag = blockIdx.y & 7;

    f32x4 acc[4][4];
#pragma unroll
    for (int i = 0; i < 4; ++i)
#pragma unroll
        for (int j = 0; j < 4; ++j) acc[i][j] = (f32x4){0.f, 0.f, 0.f, 0.f};

    for (int ks = 0; ks < 8; ++ks) {
        const int kse = (ks + stag) & 7;
        __syncthreads();                       // prev compute done

        // A: plain vector loads FIRST (cvt below then waits only on these)
        f32x4 p0[2], p1[2];
#pragma unroll
        for (int h = 0; h < 2; ++h) {
            const int c  = wave * 2 + h;       // chunk id = kki*4 + mi
            const int kki = c >> 2, mi = c & 3;
            const float* ap = A + (size_t)(m0 + mi * 16 + col_l) * 512
                                + kse * 64 + kki * 32 + quad * 8;
            p0[h] = *(const f32x4*)ap;
            p1[h] = *(const f32x4*)(ap + 4);
        }
        // B: 32 contiguous 1KB GLD16 bursts from packed P; 8 per wave
#pragma unroll
        for (int i2 = 0; i2 < 8; ++i2) {
            const int idx = wave * 8 + i2;     // 0..31
            const int kki = idx >> 4, i = idx & 15;
            const int c = (kse * 2 + kki) * 32 + nq + i;
            GLD16(P + (size_t)c * 512 + lane * 8, (char*)Bs + idx * 1024);
        }
        // convert + lane-linear ds_write (overlaps B drain)
#pragma unroll
        for (int h = 0; h < 2; ++h) {
            f16x8 av;
#pragma unroll
            for (int j = 0; j < 4; ++j) {
                av[j]     = (_Float16)(p0[h][j] * 16.f);
                av[j + 4] = (_Float16)(p1[h][j] * 16.f);
            }
            *(f16x8*)&As16[(wave * 2 + h) * 512 + lane * 8] = av;
        }
        __syncthreads();                       // B arrived + A written

#pragma unroll
        for (int kki = 0; kki < 2; ++kki) {
            f16x8 af[4];
#pragma unroll
            for (int mi = 0; mi < 4; ++mi)
                af[mi] = *(const f16x8*)&As16[(kki * 4 + mi) * 512 + lane * 8];
#pragma unroll
            for (int ni = 0; ni < 4; ++ni) {
                const f16x8 bf = *(const f16x8*)&Bs[(kki * 16 + wave * 4 + ni) * 512 + lane * 8];
#pragma unroll
                for (int mi = 0; mi < 4; ++mi)
                    acc[mi][ni] = __builtin_amdgcn_mfma_f32_16x16x32_f16(
                        af[mi], bf, acc[mi][ni], 0, 0, 0);
            }
        }
    }

    // epilogue: C/D layout col=lane&15, row=quad*4+reg
#pragma unroll
    for (int ni = 0; ni < 4; ++ni) {
        const int ncol = n0 + wave * 64 + ni * 16 + col_l;
#pragma unroll
        for (int mi = 0; mi < 4; ++mi) {
            const int mrow = m0 + mi * 16 + quad * 4;
#pragma unroll
            for (int r = 0; r < 4; ++r)
                C[(size_t)(mrow + r) * 512 + ncol] = (_Float16)acc[mi][ni][r];
        }
    }
}

// ---------------------------------------------------------------------------
// shared epilogue helpers
// ---------------------------------------------------------------------------
static __device__ __forceinline__ void emit_outputs(
    int row, int i1, int i2, float v1, float v2, float* out)
{
    out[OFF_S + row * 2 + 0] = v1;
    out[OFF_S + row * 2 + 1] = v2;
    out[OFF_N + row * 2 + 0] = (float)(i1 >> 2);
    out[OFF_N + row * 2 + 1] = (float)(i2 >> 2);
    out[OFF_L + row * 2 + 0] = (float)((i1 >> 1) & 1);
    out[OFF_L + row * 2 + 1] = (float)((i2 >> 1) & 1);
    out[OFF_R + row * 2 + 0] = (float)(i1 & 1);
    out[OFF_R + row * 2 + 1] = (float)(i2 & 1);
}

static __device__ __forceinline__ void gather_x(
    int row, int pos, int b, const int* top_z,
    const float* __restrict__ chart_h, uint16_t* __restrict__ X, int tid)
{
#pragma unroll
    for (int kq = 0; kq < 2; ++kq) {
        const int z = top_z[kq];
        const int n = z >> 2, lk = (z >> 1) & 1, rk = z & 1;
        const int lcell = level_off(n) + pos;
        const int rcell = level_off(15 - n) + pos + n + 1;
        const float* srcl = chart_h + ((size_t)(lk * B_DIM + b) * NCELLS + lcell) * SZ;
        const float* srcr = chart_h + ((size_t)(rk * B_DIM + b) * NCELLS + rcell) * SZ;
        uint16_t* dst = X + ((size_t)row * 2 + kq) * 1024;
        const int e = tid * 2;
        const float2 a = *(const float2*)(srcl + e);
        const float2 c = *(const float2*)(srcr + e);
        *(uint32_t*)(dst + e)       = (uint32_t)f2bf(a.x) | ((uint32_t)f2bf(a.y) << 16);
        *(uint32_t*)(dst + 512 + e) = (uint32_t)f2bf(c.x) | ((uint32_t)f2bf(c.y) << 16);
    }
}

// ---------------------------------------------------------------------------
// K2: cheap scores (lh f32 x T16 f16), top-3, near-tie flagging + candidate
// queue (ballot compaction). Clean rows emit outputs + gather X here.
// ---------------------------------------------------------------------------
__global__ __launch_bounds__(256)
void score_topk(const float* __restrict__ chart_h,   // f32
                const _Float16* __restrict__ T16,    // x1024
                const float* __restrict__ chart_s,
                uint32_t* __restrict__ items,        // queue entries (row<<6|z)
                int* __restrict__ rowbase,           // [1536]
                int* __restrict__ counter,           // 1 int, pre-zeroed
                int* __restrict__ flags,             // [1536]: nc (0 = clean)
                uint16_t* __restrict__ X,
                float* __restrict__ out)
{
    const int b   = blockIdx.x / L_DIM;
    const int pos = blockIdx.x % L_DIM;
    const int row = blockIdx.x;
    const int wave = threadIdx.x >> 6, lane = threadIdx.x & 63;

    __shared__ float s_sh[64];
    __shared__ int top_z[2];
    __shared__ int flag_sh;

#pragma unroll
    for (int ni = 0; ni < 4; ++ni) {
        const int n = wave * 4 + ni;
        const int lcell = level_off(n) + pos;
        const int rcell = level_off(15 - n) + pos + n + 1;

        const float* lp0 = chart_h + ((size_t)(0 * B_DIM + b) * NCELLS + lcell) * SZ + lane * 8;
        const float* lp1 = chart_h + ((size_t)(1 * B_DIM + b) * NCELLS + lcell) * SZ + lane * 8;
        const float4 l0a = *(const float4*)lp0, l0b = *(const float4*)(lp0 + 4);
        const float4 l1a = *(const float4*)lp1, l1b = *(const float4*)(lp1 + 4);
        const f16x8 t0 = *(const f16x8*)(T16 + ((size_t)(0 * B_DIM + b) * NCELLS + rcell) * SZ + lane * 8);
        const f16x8 t1 = *(const f16x8*)(T16 + ((size_t)(1 * B_DIM + b) * NCELLS + rcell) * SZ + lane * 8);

        float l0[8] = {l0a.x, l0a.y, l0a.z, l0a.w, l0b.x, l0b.y, l0b.z, l0b.w};
        float l1[8] = {l1a.x, l1a.y, l1a.z, l1a.w, l1b.x, l1b.y, l1b.z, l1b.w};

        float d00 = 0.f, d01 = 0.f, d10 = 0.f, d11 = 0.f;
#pragma unroll
        for (int j = 0; j < 8; ++j) {
            const float c0 = (float)t0[j], c1 = (float)t1[j];
            d00 += l0[j] * c0; d01 += l0[j] * c1;
            d10 += l1[j] * c0; d11 += l1[j] * c1;
        }
#pragma unroll
        for (int o = 32; o > 0; o >>= 1) {
            d00 += __shfl_down(d00, o);
            d01 += __shfl_down(d01, o);
            d10 += __shfl_down(d10, o);
            d11 += __shfl_down(d11, o);
        }
        if (lane == 0) {
            const float ls0 = chart_s[(size_t)(0 * B_DIM + b) * NCELLS + lcell];
            const float ls1 = chart_s[(size_t)(1 * B_DIM + b) * NCELLS + lcell];
            const float rs0 = chart_s[(size_t)(0 * B_DIM + b) * NCELLS + rcell];
            const float rs1 = chart_s[(size_t)(1 * B_DIM + b) * NCELLS + rcell];
            const float inv = 1.0f / 1024.0f;        // undo x1024 on T'
            s_sh[n * 4 + 0] = d00 * inv + ls0 + rs0;
            s_sh[n * 4 + 1] = d01 * inv + ls0 + rs1;
            s_sh[n * 4 + 2] = d10 * inv + ls1 + rs0;
            s_sh[n * 4 + 3] = d11 * inv + ls1 + rs1;
        }
    }
    __syncthreads();

    if (threadIdx.x < 64) {
        float v = s_sh[lane];
        if (lane == 2 || lane == 3) v = NEGF;        // penalty mask
        float v1 = v; int i1 = lane;
#pragma unroll
        for (int o = 32; o > 0; o >>= 1) {
            float ov = __shfl_down(v1, o);
            int   oi = __shfl_down(i1, o);
            if (ov > v1 || (ov == v1 && oi < i1)) { v1 = ov; i1 = oi; }
        }
        v1 = __shfl(v1, 0); i1 = __shfl(i1, 0);
        float v2 = (lane == i1) ? -3.4e38f : v; int i2 = lane;
#pragma unroll
        for (int o = 32; o > 0; o >>= 1) {
            float ov = __shfl_down(v2, o);
            int   oi = __shfl_down(i2, o);
            if (ov > v2 || (ov == v2 && oi < i2)) { v2 = ov; i2 = oi; }
        }
        v2 = __shfl(v2, 0); i2 = __shfl(i2, 0);
        float v3 = (lane == i1 || lane == i2) ? -3.4e38f : v;
#pragma unroll
        for (int o = 32; o > 0; o >>= 1) {
            const float ov = __shfl_down(v3, o);
            if (ov > v3) v3 = ov;
        }
        v3 = __shfl(v3, 0);

        const int f = (v1 - v2 < DELTA) || (v2 - v3 < DELTA);
        const bool cand = (v >= v2 - DELTA);
        const unsigned long long mask = __ballot(cand);
        const int nc_full = __popcll(mask);
        const int nc = nc_full < MAXC ? nc_full : MAXC;
        int base = 0;
        if (lane == 0) {
            flags[row] = f ? nc : 0;
            flag_sh = f;
            if (f) base = atomicAdd(counter, nc);
            rowbase[row] = base;
            top_z[0] = i1; top_z[1] = i2;
            if (!f) emit_outputs(row, i1, i2, v1, v2, out);
        }
        base = __shfl(base, 0);
        if (f && cand) {
            const int rank = __popcll(mask & ((1ull << lane) - 1ull));
            if (rank < MAXC) items[base + rank] = ((uint32_t)row << 6) | (uint32_t)lane;
        }
    }
    __syncthreads();

    if (!flag_sh)
        gather_x(row, pos, b, top_z, chart_h, X, threadIdx.x);
}

// ---------------------------------------------------------------------------
// K3a: exact f32 eval, block per ITEM PAIR (both items share the 1MB mat
// sweep). Waves split the e-range; lane owns rh[8*lane..+8) in regs.
// ---------------------------------------------------------------------------
__global__ __launch_bounds__(256)
void refine_eval(const float* __restrict__ chart_h,
                 const float* __restrict__ chart_s,
                 const float* __restrict__ mat,
                 const uint32_t* __restrict__ items,
                 const int* __restrict__ counter,
                 float* __restrict__ exval)
{
    const int total = *counter;
    const int t = threadIdx.x;
    const int wave = t >> 6, lane = t & 63;

    __shared__ float lh_sh[2][512];
    __shared__ float psum[2][4];

    for (int p = blockIdx.x; 2 * p < total; p += gridDim.x) {
        const int it0 = 2 * p;
        const int it1v = (2 * p + 1 < total);
        const uint32_t item0 = items[it0];
        const uint32_t item1 = it1v ? items[it0 + 1] : item0;

        int rowA = item0 >> 6, zA = item0 & 63;
        int bA = rowA / L_DIM, posA = rowA % L_DIM;
        int nA = zA >> 2, lkA = (zA >> 1) & 1, rkA = zA & 1;
        int lcA = level_off(nA) + posA, rcA = level_off(15 - nA) + posA + nA + 1;
        int rowB = item1 >> 6, zB = item1 & 63;
        int bB = rowB / L_DIM, posB = rowB % L_DIM;
        int nB = zB >> 2, lkB = (zB >> 1) & 1, rkB = zB & 1;
        int lcB = level_off(nB) + posB, rcB = level_off(15 - nB) + posB + nB + 1;

        const float* lhA = chart_h + ((size_t)(lkA * B_DIM + bA) * NCELLS + lcA) * SZ;
        const float* rhA = chart_h + ((size_t)(rkA * B_DIM + bA) * NCELLS + rcA) * SZ;
        const float* lhB = chart_h + ((size_t)(lkB * B_DIM + bB) * NCELLS + lcB) * SZ;
        const float* rhB = chart_h + ((size_t)(rkB * B_DIM + bB) * NCELLS + rcB) * SZ;

        __syncthreads();
        lh_sh[0][t] = lhA[t]; lh_sh[0][t + 256] = lhA[t + 256];
        lh_sh[1][t] = lhB[t]; lh_sh[1][t + 256] = lhB[t + 256];
        const float4 rA0 = *(const float4*)(rhA + lane * 8);
        const float4 rA1 = *(const float4*)(rhA + lane * 8 + 4);
        const float4 rB0 = *(const float4*)(rhB + lane * 8);
        const float4 rB1 = *(const float4*)(rhB + lane * 8 + 4);
        __syncthreads();

        const float* mb = mat + (size_t)(wave * 128) * 512 + lane * 8;
        float a00 = 0.f, a01 = 0.f, b00 = 0.f, b01 = 0.f;
        for (int e = 0; e < 128; e += 2) {
            const float4 m0 = *(const float4*)(mb + (size_t)(e + 0) * 512);
            const float4 m1 = *(const float4*)(mb + (size_t)(e + 0) * 512 + 4);
            const float4 m2 = *(const float4*)(mb + (size_t)(e + 1) * 512);
            const float4 m3 = *(const float4*)(mb + (size_t)(e + 1) * 512 + 4);
            const int eg = wave * 128 + e;
            const float lA0 = lh_sh[0][eg],     lB0 = lh_sh[1][eg];
            const float lA1 = lh_sh[0][eg + 1], lB1 = lh_sh[1][eg + 1];
            const float dA0 = m0.x*rA0.x + m0.y*rA0.y + m0.z*rA0.z + m0.w*rA0.w
                            + m1.x*rA1.x + m1.y*rA1.y + m1.z*rA1.z + m1.w*rA1.w;
            const float dB0 = m0.x*rB0.x + m0.y*rB0.y + m0.z*rB0.z + m0.w*rB0.w
                            + m1.x*rB1.x + m1.y*rB1.y + m1.z*rB1.z + m1.w*rB1.w;
            const float dA1 = m2.x*rA0.x + m2.y*rA0.y + m2.z*rA0.z + m2.w*rA0.w
                            + m3.x*rA1.x + m3.y*rA1.y + m3.z*rA1.z + m3.w*rA1.w;
            const float dB1 = m2.x*rB0.x + m2.y*rB0.y + m2.z*rB0.z + m2.w*rB0.w
                            + m3.x*rB1.x + m3.y*rB1.y + m3.z*rB1.z + m3.w*rB1.w;
            a00 += lA0 * dA0; a01 += lA1 * dA1;
            b00 += lB0 * dB0; b01 += lB1 * dB1;
        }
        float sA = a00 + a01, sB = b00 + b01;
#pragma unroll
        for (int o = 32; o > 0; o >>= 1) {
            sA += __shfl_down(sA, o);
            sB += __shfl_down(sB, o);
        }
        if (lane == 0) { psum[0][wave] = sA; psum[1][wave] = sB; }
        __syncthreads();
        if (t == 0) {
            const float lsA = chart_s[(size_t)(lkA * B_DIM + bA) * NCELLS + lcA];
            const float rsA = chart_s[(size_t)(rkA * B_DIM + bA) * NCELLS + rcA];
            exval[it0] = psum[0][0] + psum[0][1] + psum[0][2] + psum[0][3] + lsA + rsA;
            if (it1v) {
                const float lsB = chart_s[(size_t)(lkB * B_DIM + bB) * NCELLS + lcB];
                const float rsB = chart_s[(size_t)(rkB * B_DIM + bB) * NCELLS + rcB];
                exval[it0 + 1] = psum[1][0] + psum[1][1] + psum[1][2] + psum[1][3] + lsB + rsB;
            }
        }
    }
}

// ---------------------------------------------------------------------------
// K3b: per flagged row, pick exact top-2 (z-ascending list + strict '>'
// replicates jax lowest-index tie-break), emit outputs + gather X.
// ---------------------------------------------------------------------------
__global__ __launch_bounds__(256)
void refine_pick(const float* __restrict__ chart_h,
                 const uint32_t* __restrict__ items,
                 const int* __restrict__ rowbase,
                 const int* __restrict__ flags,
                 const float* __restrict__ exval,
                 uint16_t* __restrict__ X,
                 float* __restrict__ out)
{
    const int row = blockIdx.x;
    const int nc = flags[row];
    if (nc == 0) return;
    const int b = row / L_DIM, pos = row % L_DIM;
    const int t = threadIdx.x;

    __shared__ int top_z[2];

    if (t == 0) {
        const int base = rowbase[row];
        float v1 = -3.4e38f; int c1 = -1;
        for (int c = 0; c < nc; ++c) {
            const float v = exval[base + c];
            if (v > v1) { v1 = v; c1 = c; }
        }
        float v2 = -3.4e38f; int c2 = -1;
        for (int c = 0; c < nc; ++c) {
            if (c == c1) continue;
            const float v = exval[base + c];
            if (v > v2) { v2 = v; c2 = c; }
        }
        const int i1 = (int)(items[base + c1] & 63u);
        const int i2 = (int)(items[base + c2] & 63u);
        top_z[0] = i1; top_z[1] = i2;
        emit_outputs(row, i1, i2, v1, v2, out);
    }
    __syncthreads();
    gather_x(row, pos, b, top_z, chart_h, X, t);
}

// ---------------------------------------------------------------------------
// transpose_wc: WcT[o][i] = bf16(Wc[i][o])
// ---------------------------------------------------------------------------
__global__ __launch_bounds__(256)
void transpose_wc(const float* __restrict__ Wc, uint16_t* __restrict__ WcT)
{
    __shared__ float tbuf[64][65];
    const int i0 = blockIdx.x * 64;
    const int o0 = blockIdx.y * 64;
    const int c = threadIdx.x & 63, r4 = threadIdx.x >> 6;
    for (int rr = r4; rr < 64; rr += 4)
        tbuf[rr][c] = Wc[(size_t)(i0 + rr) * 512 + o0 + c];
    __syncthreads();
    for (int rr = r4; rr < 64; rr += 4)
        WcT[(size_t)(o0 + rr) * 1024 + i0 + c] = f2bf(tbuf[c][rr]);
}

// ---------------------------------------------------------------------------
// K4: H = tanh(X @ WcT^T + bc)  (bf16 in, f32 out)
// ---------------------------------------------------------------------------
typedef __bf16 bf16x8 __attribute__((ext_vector_type(8)));

__global__ __launch_bounds__(256, 2)
void gemm_compose(const uint16_t* __restrict__ A,
                  const uint16_t* __restrict__ Bm,
                  const float* __restrict__ bias,
                  float* __restrict__ C,
                  int M, int Nn, int Kk)
{
    __shared__ uint16_t As[128 * 64];
    __shared__ uint16_t Bs[128 * 64];

    const int tid  = threadIdx.x;
    const int wave = tid >> 6, lane = tid & 63;
    const int m0 = blockIdx.x * 128, n0 = blockIdx.y * 128;
    const int wm = (wave & 1) * 64, wn = (wave >> 1) * 64;
    const int col_l = lane & 15, quad = lane >> 4;
    const int lrow = lane >> 3;
    const int lcol = (lane & 7) * 8;

    f32x4 acc[4][4];
#pragma unroll
    for (int i = 0; i < 4; ++i)
#pragma unroll
        for (int j = 0; j < 4; ++j) acc[i][j] = (f32x4){0.f, 0.f, 0.f, 0.f};

    for (int k0 = 0; k0 < Kk; k0 += 64) {
        __syncthreads();
#pragma unroll
        for (int i = 0; i < 4; ++i) {
            const int q = wave * 4 + i;
            const int r = q * 8 + lrow;
            GLD16(A  + (size_t)(m0 + r) * Kk + k0 + lcol, (char*)As + q * 1024);
            GLD16(Bm + (size_t)(n0 + r) * Kk + k0 + lcol, (char*)Bs + q * 1024);
        }
        __syncthreads();
#pragma unroll
        for (int kk = 0; kk < 64; kk += 32) {
            bf16x8 af[4], bfr[4];
#pragma unroll
            for (int mi = 0; mi < 4; ++mi)
                af[mi] = *(const bf16x8*)&As[(wm + mi * 16 + col_l) * 64 + kk + quad * 8];
#pragma unroll
            for (int ni = 0; ni < 4; ++ni)
                bfr[ni] = *(const bf16x8*)&Bs[(wn + ni * 16 + col_l) * 64 + kk + quad * 8];
#pragma unroll
            for (int mi = 0; mi < 4; ++mi)
#pragma unroll
                for (int ni = 0; ni < 4; ++ni)
                    acc[mi][ni] = __builtin_amdgcn_mfma_f32_16x16x32_bf16(
                        af[mi], bfr[ni], acc[mi][ni], 0, 0, 0);
        }
    }

#pragma unroll
    for (int ni = 0; ni < 4; ++ni) {
        const int ncol = n0 + wn + ni * 16 + col_l;
        const float bv = bias[ncol];
#pragma unroll
        for (int mi = 0; mi < 4; ++mi) {
            const int mrow = m0 + wm + mi * 16 + quad * 4;
#pragma unroll
            for (int r = 0; r < 4; ++r)
                C[(size_t)(mrow + r) * Nn + ncol] = tanhf(acc[mi][ni][r] + bv);
        }
    }
}

// ---------------------------------------------------------------------------
// K5: unit-normalize H rows -> topk_h
// ---------------------------------------------------------------------------
__global__ __launch_bounds__(256)
void norm_rows(const float* __restrict__ H, float* __restrict__ out)
{
    const int row = blockIdx.x;
    const float* h = H + (size_t)row * SZ;
    const int t = threadIdx.x;
    const int wave = t >> 6, lane = t & 63;
    const float a = h[t], c = h[t + 256];
    float ss = a * a + c * c;
#pragma unroll
    for (int o = 32; o > 0; o >>= 1) ss += __shfl_down(ss, o);
    __shared__ float wsum[4];
    if (lane == 0) wsum[wave] = ss;
    __syncthreads();
    const float inv = rsqrtf(wsum[0] + wsum[1] + wsum[2] + wsum[3]);
    out[(size_t)row * SZ + t]       = a * inv;
    out[(size_t)row * SZ + t + 256] = c * inv;
}

// ---------------------------------------------------------------------------
extern "C" void kernel_launch(void* const* d_in, const int* in_sizes, int n_in,
                              void* d_out, int out_size, void* d_ws, size_t ws_size,
                              hipStream_t stream)
{
    const float* chart_h = (const float*)d_in[0];
    const float* chart_s = (const float*)d_in[1];
    const float* mat = (const float*)d_in[4];
    const float* Wc  = (const float*)d_in[5];
    const float* bc  = (const float*)d_in[6];
    float* out = (float*)d_out;

    // workspace (peak ~66.5 MB; proven ws >= 125.8 MB):
    //   T16   f16 [57856][512] @ 0            (59,244,544)  alive K1->K2
    //   MAT16 f16 packed       @ 59,244,544   (   524,288)  dead after K1
    //   ITEMS u32[49152]       @ 59,768,832   (   196,608)
    //   EXVAL f32[49152]       @ 59,965,440   (   196,608)
    //   RBASE i32[1536]        @ 60,162,048   (     6,144)
    //   CNT   i32              @ 60,168,192   (       256)
    //   FLAGS i32[1536]        @ 60,168,448   (     6,144)
    //   X     bf16[3072][1024] @ 60,174,592   ( 6,291,456)
    //   WcT   bf16[512][1024]  @ 0            (reuses T16 region after K2)
    //   H     f32 [3072][512]  @ 1,048,576    (reuses T16 region after K2)
    char* ws = (char*)d_ws;
    _Float16* T16   = (_Float16*)ws;
    _Float16* MAT16 = (_Float16*)(ws + 59244544);
    uint32_t* ITEMS = (uint32_t*)(ws + 59768832);
    float*    EXVAL = (float*)(ws + 59965440);
    int*      RBASE = (int*)(ws + 60162048);
    int*      CNT   = (int*)(ws + 60168192);
    int*      FLAGS = (int*)(ws + 60168448);
    uint16_t* X     = (uint16_t*)(ws + 60174592);
    uint16_t* WcT   = (uint16_t*)ws;
    float*    H     = (float*)(ws + 1048576);

    hipMemsetAsync(CNT, 0, 4, stream);
    // P0: packed mat16 (fragment-chunk order, f16(64*mat))
    prep_mat<<<dim3(128), 256, 0, stream>>>(mat, MAT16);
    // K1: T' = f16(16*chart_h) @ mat^T; contiguous-burst DMA, BK=64
    gemm_fused<<<dim3(2, 904), 256, 0, stream>>>(chart_h, MAT16, T16);
    // K2: cheap scores + top3 + candidate queue; outputs + X for clean rows
    score_topk<<<dim3(B_DIM * L_DIM), 256, 0, stream>>>(chart_h, T16, chart_s,
                                                        ITEMS, RBASE, CNT, FLAGS, X, out);
    // (T16/MAT16 dead from here; WcT/H overlay T16 region)
    transpose_wc<<<dim3(16, 8), 256, 0, stream>>>(Wc, WcT);
    // K3a: exact eval, block per item pair (mat shared within pair)
    refine_eval<<<dim3(1024), 256, 0, stream>>>(chart_h, chart_s, mat, ITEMS, CNT, EXVAL);
    // K3b: per-row exact top-2 + outputs + X
    refine_pick<<<dim3(B_DIM * L_DIM), 256, 0, stream>>>(chart_h, ITEMS, RBASE, FLAGS,
                                                         EXVAL, X, out);
    // K4: H = tanh(X @ WcT^T + bc)
    gemm_compose<<<dim3(24, 4), 256, 0, stream>>>(X, WcT, bc, H, 3072, 512, 1024);
    // K5: topk_h = H / ||H||
    norm_rows<<<dim3(3072), 256, 0, stream>>>(H, out);
}